// Round 2
// baseline (521.916 us; speedup 1.0000x reference)
//
#include <hip/hip_runtime.h>
#include <hip/hip_bf16.h>

// FP8Linear: out[M=8192][N=4096] = X[M][K=4096] @ W[N][K]^T, W = qweight*scale.
// fp32->bf16 cvt into d_ws, then 256x256-tile bf16 MFMA GEMM with a
// 4-phase/K-tile pipeline, counted vmcnt, conflict-free swizzled LDS.

typedef __attribute__((ext_vector_type(4))) float  f32x4;
typedef __attribute__((ext_vector_type(8))) short  bf16x8;
typedef __attribute__((ext_vector_type(8))) unsigned short u16x8;

static constexpr int Mdim = 8192;   // B*S
static constexpr int Ndim = 4096;   // D_OUT
static constexpr int Kdim = 4096;   // D_IN
static constexpr int NT   = Kdim / 32;   // 128 K-tiles of BK=32

__device__ __forceinline__ unsigned short f2bf(float f) {
  unsigned u = __builtin_bit_cast(unsigned, f);
  u += 0x7fffu + ((u >> 16) & 1u);   // RNE (finite inputs)
  return (unsigned short)(u >> 16);
}

__device__ __forceinline__ void gload16(const unsigned short* g, char* l) {
  __builtin_amdgcn_global_load_lds(
      (const __attribute__((address_space(1))) unsigned int*)g,
      (__attribute__((address_space(3))) unsigned int*)l, 16, 0, 0);
}

// ---------------- conversion kernels (memory-bound) ----------------

__global__ __launch_bounds__(256) void cvt_x_kernel(const float* __restrict__ in,
                                                    unsigned short* __restrict__ out,
                                                    long n8) {
  long i = (long)blockIdx.x * 256 + threadIdx.x;
  const long stride = (long)gridDim.x * 256;
  for (; i < n8; i += stride) {
    f32x4 a = ((const f32x4*)in)[2 * i];
    f32x4 b = ((const f32x4*)in)[2 * i + 1];
    u16x8 o;
    o[0] = f2bf(a[0]); o[1] = f2bf(a[1]); o[2] = f2bf(a[2]); o[3] = f2bf(a[3]);
    o[4] = f2bf(b[0]); o[5] = f2bf(b[1]); o[6] = f2bf(b[2]); o[7] = f2bf(b[3]);
    ((u16x8*)out)[i] = o;
  }
}

__global__ __launch_bounds__(256) void cvt_w_kernel(const float* __restrict__ qw,
                                                    const float* __restrict__ scale,
                                                    unsigned short* __restrict__ out,
                                                    long n8) {
  long i = (long)blockIdx.x * 256 + threadIdx.x;
  const long stride = (long)gridDim.x * 256;
  for (; i < n8; i += stride) {
    const int row = (int)(i >> 9);           // (i*8)/4096
    const float s = scale[row];
    f32x4 a = ((const f32x4*)qw)[2 * i];
    f32x4 b = ((const f32x4*)qw)[2 * i + 1];
    u16x8 o;
    o[0] = f2bf(a[0] * s); o[1] = f2bf(a[1] * s); o[2] = f2bf(a[2] * s); o[3] = f2bf(a[3] * s);
    o[4] = f2bf(b[0] * s); o[5] = f2bf(b[1] * s); o[6] = f2bf(b[2] * s); o[7] = f2bf(b[3] * s);
    ((u16x8*)out)[i] = o;
  }
}

// ---------------- GEMM ----------------
// LDS (64 KB static): A at 0, B at 32768. Per matrix: [buf(2)][16 KB tile].
// Tile layout, pair-packed + swizzled: logical (row r in 0..255, c16 in 0..3
// 16B-chunks of the 32-wide K slice) lives at byte
//   (r>>1)*128 + ((((r&1)<<2)|c16) ^ ((r>>1)&7))*16
// -> staging writes are LINEAR (inverse swizzle applied to global source),
//    ds_read_b128 spreads 64 lanes uniformly 8-per-16B-slot (conflict-free).
// Halves: h0 = rows 0..127 (bytes 0..8191), h1 = rows 128..255.
//
// Waves: 8 = 2(M) x 4(N), INTERLEAVED tiling: m-frag i at row i*32+wr*16,
// n-frag j at col j*64+wc*16  =>  phase quadrant (i<4 / j<2) touches exactly
// one half for every wave.
//
// Per K-tile t (buf = t&1), 4 phases, 8 MFMA each:
//  p1: stage A-h1(t+1)->buf^1 | read af0-3,bf0 | mfma i0-3 x j0-1 | barrier
//  p2: stage B-h1(t+1)->buf^1 | read bf1       | mfma i0-3 x j2-3 | barrier
//  p3: stage A-h0(t+2)->buf   | read af4-7     | mfma i4-7 x j2-3 | barrier
//  p4: stage B-h0(t+2)->buf   |                | mfma i4-7 x j0-1 | vmcnt(2); barrier
// Stage targets are only regions whose last reader finished before a
// preceding barrier; boundary vmcnt(2) (in-order) guarantees tile t+1 resident.

template<bool S12, bool S34, int VMC>
__device__ __forceinline__ void do_tile(int t, int buf,
                                        const unsigned short* aH0, const unsigned short* aH1,
                                        const unsigned short* bH0, const unsigned short* bH1,
                                        char* ldsA, char* ldsB, int w,
                                        int offA, int offB, f32x4 (&acc)[8][4]) {
  const int bufB = buf * 16384;
  bf16x8 af[4], bf0[2], bf1[2];

  // ---- phase 1 ----
  if (S12) gload16(aH1 + (size_t)(t + 1) * 32, ldsA + (bufB ^ 16384) + 8192 + w * 1024);
#pragma unroll
  for (int i = 0; i < 4; ++i) af[i] = *(const bf16x8*)(ldsA + bufB + i * 2048 + offA);
#pragma unroll
  for (int j = 0; j < 2; ++j) bf0[j] = *(const bf16x8*)(ldsB + bufB + j * 4096 + offB);
  __builtin_amdgcn_s_setprio(1);
#pragma unroll
  for (int i = 0; i < 4; ++i)
#pragma unroll
    for (int j = 0; j < 2; ++j)
      acc[i][j] = __builtin_amdgcn_mfma_f32_16x16x32_bf16(af[i], bf0[j], acc[i][j], 0, 0, 0);
  __builtin_amdgcn_s_setprio(0);
  __builtin_amdgcn_s_barrier();

  // ---- phase 2 ----
  if (S12) gload16(bH1 + (size_t)(t + 1) * 32, ldsB + (bufB ^ 16384) + 8192 + w * 1024);
#pragma unroll
  for (int j = 0; j < 2; ++j) bf1[j] = *(const bf16x8*)(ldsB + bufB + (j + 2) * 4096 + offB);
  __builtin_amdgcn_s_setprio(1);
#pragma unroll
  for (int i = 0; i < 4; ++i)
#pragma unroll
    for (int j = 0; j < 2; ++j)
      acc[i][j + 2] = __builtin_amdgcn_mfma_f32_16x16x32_bf16(af[i], bf1[j], acc[i][j + 2], 0, 0, 0);
  __builtin_amdgcn_s_setprio(0);
  __builtin_amdgcn_s_barrier();

  // ---- phase 3 ----
  if (S34) gload16(aH0 + (size_t)(t + 2) * 32, ldsA + bufB + 0 + w * 1024);
#pragma unroll
  for (int i = 0; i < 4; ++i) af[i] = *(const bf16x8*)(ldsA + bufB + (i + 4) * 2048 + offA);
  __builtin_amdgcn_s_setprio(1);
#pragma unroll
  for (int i = 0; i < 4; ++i)
#pragma unroll
    for (int j = 0; j < 2; ++j)
      acc[i + 4][j + 2] = __builtin_amdgcn_mfma_f32_16x16x32_bf16(af[i], bf1[j], acc[i + 4][j + 2], 0, 0, 0);
  __builtin_amdgcn_s_setprio(0);
  __builtin_amdgcn_s_barrier();

  // ---- phase 4 ----
  if (S34) gload16(bH0 + (size_t)(t + 2) * 32, ldsB + bufB + 0 + w * 1024);
  __builtin_amdgcn_s_setprio(1);
#pragma unroll
  for (int i = 0; i < 4; ++i)
#pragma unroll
    for (int j = 0; j < 2; ++j)
      acc[i + 4][j] = __builtin_amdgcn_mfma_f32_16x16x32_bf16(af[i], bf0[j], acc[i + 4][j], 0, 0, 0);
  __builtin_amdgcn_s_setprio(0);
  if constexpr (VMC == 2) asm volatile("s_waitcnt vmcnt(2)" ::: "memory");
  else if constexpr (VMC == 0) asm volatile("s_waitcnt vmcnt(0)" ::: "memory");
  if constexpr (VMC >= 0) __builtin_amdgcn_s_barrier();
}

__global__ __launch_bounds__(512, 2) void gemm_kernel(const unsigned short* __restrict__ A,
                                                      const unsigned short* __restrict__ B,
                                                      float* __restrict__ C) {
  __shared__ char lds[65536];

  const int th = threadIdx.x;
  const int w  = th >> 6, l = th & 63;
  const int wr = w & 1, wc = w >> 1;

  // XCD-bijective swizzle (512 % 8 == 0)
  int wg = (int)blockIdx.x;
  wg = (wg & 7) * 64 + (wg >> 3);
  const int bm = wg >> 4, bn = wg & 15;   // 32 x 16 blocks

  // staging source (inverse-swizzled): thread th fills LDS byte th*16 of a half
  const int u    = (th & 7) ^ ((th >> 3) & 7);
  const int srow = 2 * (th >> 3) + (u >> 2);
  const int scol = (u & 3) * 8;
  const unsigned short* aH0 = A + (size_t)(bm * 256 + srow) * Kdim + scol;
  const unsigned short* aH1 = aH0 + (size_t)128 * Kdim;
  const unsigned short* bH0 = B + (size_t)(bn * 256 + srow) * Kdim + scol;
  const unsigned short* bH1 = bH0 + (size_t)128 * Kdim;

  char* ldsA = lds;
  char* ldsB = lds + 32768;

  // fragment read offsets (swizzled); frag = logical (row base+l&15, c16 = l>>4)
  const int amr0 = wr * 16 + (l & 15);
  const int bnr0 = wc * 16 + (l & 15);
  const int c16  = l >> 4;
  const int SA   = (((amr0 & 1) << 2) | c16) ^ ((amr0 >> 1) & 7);
  const int SB   = (((bnr0 & 1) << 2) | c16) ^ ((bnr0 >> 1) & 7);
  const int offA = (amr0 >> 1) * 128 + SA * 16;
  const int offB = (bnr0 >> 1) * 128 + SB * 16;

  f32x4 acc[8][4] = {};

  // prologue: tile0 fully + tile1 h0s; vmcnt(2) leaves exactly those 2 in flight
  gload16(aH0, ldsA + 0 + w * 1024);
  gload16(bH0, ldsB + 0 + w * 1024);
  gload16(aH1, ldsA + 8192 + w * 1024);
  gload16(bH1, ldsB + 8192 + w * 1024);
  gload16(aH0 + 32, ldsA + 16384 + w * 1024);
  gload16(bH0 + 32, ldsB + 16384 + w * 1024);
  asm volatile("s_waitcnt vmcnt(2)" ::: "memory");
  __builtin_amdgcn_s_barrier();

  for (int t = 0; t < NT - 2; ++t)
    do_tile<true, true, 2>(t, t & 1, aH0, aH1, bH0, bH1, ldsA, ldsB, w, offA, offB, acc);
  do_tile<true, false, 0>(NT - 2, (NT - 2) & 1, aH0, aH1, bH0, bH1, ldsA, ldsB, w, offA, offB, acc);
  do_tile<false, false, -1>(NT - 1, (NT - 1) & 1, aH0, aH1, bH0, bH1, ldsA, ldsB, w, offA, offB, acc);

  // epilogue: C/D layout col = l&15, row = (l>>4)*4 + reg
  const int r0 = (l >> 4) * 4;
  const int cc = l & 15;
#pragma unroll
  for (int i = 0; i < 8; ++i)
#pragma unroll
    for (int j = 0; j < 4; ++j) {
      float* cp = C + (size_t)(bm * 256 + i * 32 + wr * 16 + r0) * Ndim
                    + bn * 256 + j * 64 + wc * 16 + cc;
#pragma unroll
      for (int rr = 0; rr < 4; ++rr) cp[(size_t)rr * Ndim] = acc[i][j][rr];
    }
}

extern "C" void kernel_launch(void* const* d_in, const int* in_sizes, int n_in,
                              void* d_out, int out_size, void* d_ws, size_t ws_size,
                              hipStream_t stream) {
  const float* x     = (const float*)d_in[0];
  const float* qw    = (const float*)d_in[1];
  const float* scale = (const float*)d_in[2];
  float* out = (float*)d_out;

  unsigned short* xb = (unsigned short*)d_ws;                 // 67.1 MB
  unsigned short* wb = xb + (size_t)Mdim * Kdim;              // +33.6 MB

  cvt_x_kernel<<<2048, 256, 0, stream>>>(x, xb, (long)Mdim * Kdim / 8);
  cvt_w_kernel<<<2048, 256, 0, stream>>>(qw, scale, wb, (long)Ndim * Kdim / 8);

  gemm_kernel<<<(Mdim / 256) * (Ndim / 256), 512, 0, stream>>>(xb, wb, out);
}

// Round 3
// 473.683 us; speedup vs baseline: 1.1018x; 1.1018x over previous
//
#include <hip/hip_runtime.h>
#include <hip/hip_bf16.h>

// FP8Linear: out[M=8192][N=4096] = X @ (qweight*scale)^T.
// One fused fp32->bf16 cvt kernel, then 256x256/BK=64 bf16 MFMA GEMM,
// m201-style 8-phase schedule, counted vmcnt(6), XOR-swizzled LDS, 128KB LDS.

typedef __attribute__((ext_vector_type(4))) float  f32x4;
typedef __attribute__((ext_vector_type(8))) short  bf16x8;
typedef __attribute__((ext_vector_type(8))) unsigned short u16x8;

static constexpr int Mdim = 8192, Ndim = 4096, Kdim = 4096;
static constexpr int ITERS = Kdim / 128;   // 32 iterations, 2 K-tiles (BK=64) each

__device__ __forceinline__ unsigned short f2bf(float f) {
  unsigned u = __builtin_bit_cast(unsigned, f);
  u += 0x7fffu + ((u >> 16) & 1u);   // RNE (finite inputs)
  return (unsigned short)(u >> 16);
}

__device__ __forceinline__ void gload16(const unsigned short* g, const char* l) {
  __builtin_amdgcn_global_load_lds(
      (const __attribute__((address_space(1))) unsigned int*)g,
      (__attribute__((address_space(3))) unsigned int*)(char*)l, 16, 0, 0);
}

// ---------------- fused conversion (memory-bound, one chunk of 8 per thread) ----------------

__global__ __launch_bounds__(256) void cvt_kernel(const float* __restrict__ x,
                                                  const float* __restrict__ qw,
                                                  const float* __restrict__ scale,
                                                  unsigned short* __restrict__ xb,
                                                  unsigned short* __restrict__ wb) {
  const long NX = (long)Mdim * Kdim / 8;   // 4194304
  long i = (long)blockIdx.x * 256 + threadIdx.x;
  if (i < NX) {
    f32x4 a = ((const f32x4*)x)[2 * i];
    f32x4 b = ((const f32x4*)x)[2 * i + 1];
    u16x8 o;
    o[0] = f2bf(a[0]); o[1] = f2bf(a[1]); o[2] = f2bf(a[2]); o[3] = f2bf(a[3]);
    o[4] = f2bf(b[0]); o[5] = f2bf(b[1]); o[6] = f2bf(b[2]); o[7] = f2bf(b[3]);
    ((u16x8*)xb)[i] = o;
  } else {
    long j = i - NX;
    const float s = scale[j >> 9];          // 512 chunks per weight row
    f32x4 a = ((const f32x4*)qw)[2 * j];
    f32x4 b = ((const f32x4*)qw)[2 * j + 1];
    u16x8 o;
    o[0] = f2bf(a[0] * s); o[1] = f2bf(a[1] * s); o[2] = f2bf(a[2] * s); o[3] = f2bf(a[3] * s);
    o[4] = f2bf(b[0] * s); o[5] = f2bf(b[1] * s); o[6] = f2bf(b[2] * s); o[7] = f2bf(b[3] * s);
    ((u16x8*)wb)[j] = o;
  }
}

// ---------------- GEMM ----------------
// LDS 128KB dynamic: A tiles at [0,64K) (buf0=even K-tile, buf1=odd), B at [64K,128K).
// Tile (256 rows x 64 K, 32KB): logical (row r, 16B-chunk ch in 0..7) at byte
//   r*128 + (ch ^ (r&7))*16   -> staging dest LINEAR (inverse swizzle on global src),
//   frag ds_read_b128 distribution == canonical linear pattern (0 extra conflicts).
// Waves 8 = 2M x 4N interleaved: m-frag i at row i*32+wr*16 (i<4 -> h0, i>=4 -> h1),
// n-frag j at col j*64+wc*16 (j<2 -> h0). Per phase: one C-quadrant x K=64 = 16 MFMA.
//
// Phase -> {ds_read | stage (2 gload_lds, 1 half-tile)}:   [tiles t=2i, t+1 resident]
//  ph1: RD A0h0,B0h0 | STG A1h1(t+1)   ph5: RD A1h0,B1h0 | STG A0h1(t+2)
//  ph2: RD B0h1      | STG A0h0(t+2)   ph6: RD B1h1      | STG A1h0(t+3)
//  ph3: RD A0h1      | STG B0h0(t+2)   ph7: RD A1h1      | STG B1h0(t+3)
//  ph4: (regs only)  | STG B0h1(t+2)   ph8: (regs only)  | STG B1h1(t+3)
// Every staged region's last ds_read is >=1 barrier earlier. vmcnt(6) at ph4 end
// drains through ph1's stage -> tile t+1 resident for ph5; vmcnt(6) at ph8 end
// drains through ph5's stage -> tile t+2 resident for next ph1. Never vmcnt(0) mid-loop.

#define PBAR() do { __builtin_amdgcn_s_barrier(); \
                    asm volatile("s_waitcnt lgkmcnt(0)" ::: "memory"); } while (0)

#define MMQ(mo, no, bf) do { \
  __builtin_amdgcn_s_setprio(1); \
  _Pragma("unroll") for (int m_ = 0; m_ < 4; ++m_) \
  _Pragma("unroll") for (int n_ = 0; n_ < 2; ++n_) \
  _Pragma("unroll") for (int s_ = 0; s_ < 2; ++s_) \
    acc[(mo) + m_][(no) + n_] = __builtin_amdgcn_mfma_f32_16x16x32_bf16( \
        af[m_][s_], bf[n_][s_], acc[(mo) + m_][(no) + n_], 0, 0, 0); \
  __builtin_amdgcn_s_setprio(0); \
} while (0)

#define RDA(base, mb) do { \
  _Pragma("unroll") for (int m_ = 0; m_ < 4; ++m_) { \
    af[m_][0] = *(const bf16x8*)((base) + ((mb) + m_) * 4096 + rowbA + cs0); \
    af[m_][1] = *(const bf16x8*)((base) + ((mb) + m_) * 4096 + rowbA + (cs0 ^ 64)); \
  } } while (0)

#define RDB(base, nb, bf) do { \
  _Pragma("unroll") for (int n_ = 0; n_ < 2; ++n_) { \
    bf[n_][0] = *(const bf16x8*)((base) + ((nb) + n_) * 8192 + rowbB + cs0); \
    bf[n_][1] = *(const bf16x8*)((base) + ((nb) + n_) * 8192 + rowbB + (cs0 ^ 64)); \
  } } while (0)

#define STG(p, h, T, base) do { \
  gload16((p) + ((size_t)((h) * 128)) * Kdim + (T) * 64, (base) + (h) * 16384 + wb1024); \
  gload16((p) + ((size_t)((h) * 128 + 64)) * Kdim + (T) * 64, (base) + (h) * 16384 + 8192 + wb1024); \
} while (0)

__global__ __launch_bounds__(512, 2) void gemm_kernel(const unsigned short* __restrict__ A,
                                                      const unsigned short* __restrict__ B,
                                                      float* __restrict__ C) {
  extern __shared__ char lds[];
  char* A0 = lds;                  // even K-tile A (32KB)
  char* A1 = lds + 32768;          // odd  K-tile A
  char* B0 = lds + 65536;
  char* B1 = lds + 98304;

  const int th = threadIdx.x, w = th >> 6, l = th & 63;
  const int wr = w & 1, wc = w >> 1;
  const int wb1024 = w * 1024;

  // XCD-bijective swizzle (512 blocks, 512 % 8 == 0)
  int wg = (int)blockIdx.x;
  wg = (wg & 7) * 64 + (wg >> 3);
  const int bm = wg >> 4, bn = wg & 15;

  // staging source (inverse-swizzled): thread th supplies LDS-linear byte th*16 of a half
  const int kc8 = ((th & 7) ^ ((th >> 3) & 7)) * 8;
  const unsigned short* pA = A + (size_t)(bm * 256 + (th >> 3)) * Kdim + kc8;
  const unsigned short* pB = B + (size_t)(bn * 256 + (th >> 3)) * Kdim + kc8;

  // fragment read offsets (swizzled)
  const int rowbA = (wr * 16 + (l & 15)) * 128;
  const int rowbB = (wc * 16 + (l & 15)) * 128;
  const int cs0   = ((l >> 4) ^ (l & 7)) * 16;   // kstep1 offset = cs0 ^ 64

  f32x4 acc[8][4] = {};
  bf16x8 af[4][2], bf0[2][2], bf1[2][2];

  // prologue: tile0 fully (8 loads, oldest), then tile1 A-h0,B-h0,B-h1 (6 loads)
  STG(pA, 0, 0, A0); STG(pA, 1, 0, A0);
  STG(pB, 0, 0, B0); STG(pB, 1, 0, B0);
  STG(pA, 0, 1, A1);
  STG(pB, 0, 1, B1);
  STG(pB, 1, 1, B1);
  asm volatile("s_waitcnt vmcnt(6)" ::: "memory");
  __builtin_amdgcn_s_barrier();

#pragma unroll 1
  for (int i = 0; i < ITERS - 1; ++i) {
    const int t1 = 2 * i + 1, t2 = 2 * i + 2, t3 = 2 * i + 3;
    // ph1
    RDA(A0, 0); RDB(B0, 0, bf0);
    STG(pA, 1, t1, A1);
    PBAR(); MMQ(0, 0, bf0); __builtin_amdgcn_s_barrier();
    // ph2
    RDB(B0, 2, bf1);
    STG(pA, 0, t2, A0);
    PBAR(); MMQ(0, 2, bf1); __builtin_amdgcn_s_barrier();
    // ph3
    RDA(A0, 4);
    STG(pB, 0, t2, B0);
    PBAR(); MMQ(4, 2, bf1); __builtin_amdgcn_s_barrier();
    // ph4
    STG(pB, 1, t2, B0);
    PBAR(); MMQ(4, 0, bf0);
    asm volatile("s_waitcnt vmcnt(6)" ::: "memory");
    __builtin_amdgcn_s_barrier();
    // ph5
    RDA(A1, 0); RDB(B1, 0, bf0);
    STG(pA, 1, t2, A0);
    PBAR(); MMQ(0, 0, bf0); __builtin_amdgcn_s_barrier();
    // ph6
    RDB(B1, 2, bf1);
    STG(pA, 0, t3, A1);
    PBAR(); MMQ(0, 2, bf1); __builtin_amdgcn_s_barrier();
    // ph7
    RDA(A1, 4);
    STG(pB, 0, t3, B1);
    PBAR(); MMQ(4, 2, bf1); __builtin_amdgcn_s_barrier();
    // ph8
    STG(pB, 1, t3, B1);
    PBAR(); MMQ(4, 0, bf0);
    asm volatile("s_waitcnt vmcnt(6)" ::: "memory");
    __builtin_amdgcn_s_barrier();
  }

  // tail iteration (tiles 62,63): stage only ph1 (A-h1 of 63), vmcnt(0) at ph4
  RDA(A0, 0); RDB(B0, 0, bf0);
  STG(pA, 1, 63, A1);
  PBAR(); MMQ(0, 0, bf0); __builtin_amdgcn_s_barrier();
  RDB(B0, 2, bf1);
  PBAR(); MMQ(0, 2, bf1); __builtin_amdgcn_s_barrier();
  RDA(A0, 4);
  PBAR(); MMQ(4, 2, bf1); __builtin_amdgcn_s_barrier();
  PBAR(); MMQ(4, 0, bf0);
  asm volatile("s_waitcnt vmcnt(0)" ::: "memory");
  __builtin_amdgcn_s_barrier();
  RDA(A1, 0); RDB(B1, 0, bf0);
  PBAR(); MMQ(0, 0, bf0); __builtin_amdgcn_s_barrier();
  RDB(B1, 2, bf1);
  PBAR(); MMQ(0, 2, bf1); __builtin_amdgcn_s_barrier();
  RDA(A1, 4);
  PBAR(); MMQ(4, 2, bf1); __builtin_amdgcn_s_barrier();
  PBAR(); MMQ(4, 0, bf0);

  // epilogue: C/D layout col = l&15, row = (l>>4)*4 + reg
  const int r0 = (l >> 4) * 4;
  const int cc = l & 15;
#pragma unroll
  for (int i = 0; i < 8; ++i)
#pragma unroll
    for (int j = 0; j < 4; ++j) {
      float* cp = C + (size_t)(bm * 256 + i * 32 + wr * 16 + r0) * Ndim
                    + bn * 256 + j * 64 + wc * 16 + cc;
#pragma unroll
      for (int rr = 0; rr < 4; ++rr) cp[(size_t)rr * Ndim] = acc[i][j][rr];
    }
}

extern "C" void kernel_launch(void* const* d_in, const int* in_sizes, int n_in,
                              void* d_out, int out_size, void* d_ws, size_t ws_size,
                              hipStream_t stream) {
  const float* x     = (const float*)d_in[0];
  const float* qw    = (const float*)d_in[1];
  const float* scale = (const float*)d_in[2];
  float* out = (float*)d_out;

  unsigned short* xb = (unsigned short*)d_ws;                 // 67.1 MB
  unsigned short* wb = xb + (size_t)Mdim * Kdim;              // +33.6 MB

  (void)hipFuncSetAttribute((const void*)gemm_kernel,
                            hipFuncAttributeMaxDynamicSharedMemorySize, 131072);

  const long nchunks = (long)Mdim * Kdim / 8 + (long)Ndim * Kdim / 8;  // 6291456
  cvt_kernel<<<(int)(nchunks / 256), 256, 0, stream>>>(x, qw, scale, xb, wb);

  gemm_kernel<<<(Mdim / 256) * (Ndim / 256), 512, 131072, stream>>>(xb, wb, out);
}

// Round 5
// 469.075 us; speedup vs baseline: 1.1126x; 1.0098x over previous
//
#include <hip/hip_runtime.h>
#include <hip/hip_bf16.h>

// FP8Linear: out[M=8192][N=4096] = X @ (qweight*scale)^T.
// One fused fp32->bf16 cvt kernel, then 256x256/BK=64 bf16 MFMA GEMM,
// m201-style 8-phase schedule, counted vmcnt(6), XOR-swizzled LDS, 128KB LDS,
// LDS-shuffled coalesced nontemporal fp32 epilogue.

typedef __attribute__((ext_vector_type(4))) float  f32x4;
typedef __attribute__((ext_vector_type(8))) short  bf16x8;
typedef __attribute__((ext_vector_type(8))) unsigned short u16x8;

static constexpr int Mdim = 8192, Ndim = 4096, Kdim = 4096;
static constexpr int ITERS = Kdim / 128;   // 32 iterations, 2 K-tiles (BK=64) each

__device__ __forceinline__ unsigned short f2bf(float f) {
  unsigned u = __builtin_bit_cast(unsigned, f);
  u += 0x7fffu + ((u >> 16) & 1u);   // RNE (finite inputs)
  return (unsigned short)(u >> 16);
}

__device__ __forceinline__ void gload16(const unsigned short* g, const char* l) {
  __builtin_amdgcn_global_load_lds(
      (const __attribute__((address_space(1))) unsigned int*)g,
      (__attribute__((address_space(3))) unsigned int*)(char*)l, 16, 0, 0);
}

// ---------------- fused conversion (memory-bound, one chunk of 8 per thread) ----------------

__global__ __launch_bounds__(256) void cvt_kernel(const float* __restrict__ x,
                                                  const float* __restrict__ qw,
                                                  const float* __restrict__ scale,
                                                  unsigned short* __restrict__ xb,
                                                  unsigned short* __restrict__ wb) {
  const long NX = (long)Mdim * Kdim / 8;   // 4194304
  long i = (long)blockIdx.x * 256 + threadIdx.x;
  if (i < NX) {
    f32x4 a = ((const f32x4*)x)[2 * i];
    f32x4 b = ((const f32x4*)x)[2 * i + 1];
    u16x8 o;
    o[0] = f2bf(a[0]); o[1] = f2bf(a[1]); o[2] = f2bf(a[2]); o[3] = f2bf(a[3]);
    o[4] = f2bf(b[0]); o[5] = f2bf(b[1]); o[6] = f2bf(b[2]); o[7] = f2bf(b[3]);
    ((u16x8*)xb)[i] = o;
  } else {
    long j = i - NX;
    const float s = scale[j >> 9];          // 512 chunks per weight row
    f32x4 a = ((const f32x4*)qw)[2 * j];
    f32x4 b = ((const f32x4*)qw)[2 * j + 1];
    u16x8 o;
    o[0] = f2bf(a[0] * s); o[1] = f2bf(a[1] * s); o[2] = f2bf(a[2] * s); o[3] = f2bf(a[3] * s);
    o[4] = f2bf(b[0] * s); o[5] = f2bf(b[1] * s); o[6] = f2bf(b[2] * s); o[7] = f2bf(b[3] * s);
    ((u16x8*)wb)[j] = o;
  }
}

// ---------------- GEMM ----------------
// LDS 128KB dynamic: A tiles at [0,64K) (buf0=even K-tile, buf1=odd), B at [64K,128K).
// Tile (256 rows x 64 K, 32KB): logical (row r, 16B-chunk ch in 0..7) at byte
//   r*128 + (ch ^ (r&7))*16   -> staging dest LINEAR (inverse swizzle on global src).
// Waves 8 = 2M x 4N interleaved: m-frag i at row i*32+wr*16 (i<4 -> h0, i>=4 -> h1),
// n-frag j at col j*64+wc*16 (j<2 -> h0). Per phase: one C-quadrant x K=64 = 16 MFMA.
// Phase -> {ds_read | stage}: ph1: A0h0,B0h0 | A1h1(t+1); ph2: B0h1 | A0h0(t+2);
// ph3: A0h1 | B0h0(t+2); ph4: - | B0h1(t+2); ph5-8 mirror on odd tile.
// vmcnt(6) only at ph4/ph8 (tile t+1 resident for ph5 / t+2 for next ph1).

#define PBAR() do { __builtin_amdgcn_s_barrier(); \
                    asm volatile("s_waitcnt lgkmcnt(0)" ::: "memory"); } while (0)
#define PACE() asm volatile("s_waitcnt lgkmcnt(8)" ::: "memory")

#define MMQ(mo, no, bf) do { \
  __builtin_amdgcn_s_setprio(1); \
  _Pragma("unroll") for (int m_ = 0; m_ < 4; ++m_) \
  _Pragma("unroll") for (int n_ = 0; n_ < 2; ++n_) \
  _Pragma("unroll") for (int s_ = 0; s_ < 2; ++s_) \
    acc[(mo) + m_][(no) + n_] = __builtin_amdgcn_mfma_f32_16x16x32_bf16( \
        af[m_][s_], bf[n_][s_], acc[(mo) + m_][(no) + n_], 0, 0, 0); \
  __builtin_amdgcn_s_setprio(0); \
} while (0)

#define RDA(base, mb) do { \
  _Pragma("unroll") for (int m_ = 0; m_ < 4; ++m_) { \
    af[m_][0] = *(const bf16x8*)((base) + ((mb) + m_) * 4096 + rowbA + cs0); \
    af[m_][1] = *(const bf16x8*)((base) + ((mb) + m_) * 4096 + rowbA + (cs0 ^ 64)); \
  } } while (0)

#define RDB(base, nb, bf) do { \
  _Pragma("unroll") for (int n_ = 0; n_ < 2; ++n_) { \
    bf[n_][0] = *(const bf16x8*)((base) + ((nb) + n_) * 8192 + rowbB + cs0); \
    bf[n_][1] = *(const bf16x8*)((base) + ((nb) + n_) * 8192 + rowbB + (cs0 ^ 64)); \
  } } while (0)

#define STG(p, h, T, base) do { \
  gload16((p) + ((size_t)((h) * 128)) * Kdim + (T) * 64, (base) + (h) * 16384 + wb1024); \
  gload16((p) + ((size_t)((h) * 128 + 64)) * Kdim + (T) * 64, (base) + (h) * 16384 + 8192 + wb1024); \
} while (0)

__global__ __launch_bounds__(512, 2) void gemm_kernel(const unsigned short* __restrict__ A,
                                                      const unsigned short* __restrict__ B,
                                                      float* __restrict__ C) {
  extern __shared__ char lds[];
  char* A0 = lds;                  // even K-tile A (32KB)
  char* A1 = lds + 32768;          // odd  K-tile A
  char* B0 = lds + 65536;
  char* B1 = lds + 98304;

  const int th = threadIdx.x, w = th >> 6, l = th & 63;
  const int wr = w & 1, wc = w >> 1;
  const int wb1024 = w * 1024;

  // XCD-bijective swizzle (512 blocks, 512 % 8 == 0)
  int wg = (int)blockIdx.x;
  wg = (wg & 7) * 64 + (wg >> 3);
  const int bm = wg >> 4, bn = wg & 15;

  // staging source (inverse-swizzled): thread th supplies LDS-linear byte th*16 of a half
  const int kc8 = ((th & 7) ^ ((th >> 3) & 7)) * 8;
  const unsigned short* pA = A + (size_t)(bm * 256 + (th >> 3)) * Kdim + kc8;
  const unsigned short* pB = B + (size_t)(bn * 256 + (th >> 3)) * Kdim + kc8;

  // fragment read offsets (swizzled)
  const int rowbA = (wr * 16 + (l & 15)) * 128;
  const int rowbB = (wc * 16 + (l & 15)) * 128;
  const int cs0   = ((l >> 4) ^ (l & 7)) * 16;   // kstep1 offset = cs0 ^ 64

  f32x4 acc[8][4] = {};
  bf16x8 af[4][2], bf0[2][2], bf1[2][2];

  // prologue: tile0 fully (8 loads, oldest), then tile1 A-h0,B-h0,B-h1 (6 loads)
  STG(pA, 0, 0, A0); STG(pA, 1, 0, A0);
  STG(pB, 0, 0, B0); STG(pB, 1, 0, B0);
  STG(pA, 0, 1, A1);
  STG(pB, 0, 1, B1);
  STG(pB, 1, 1, B1);
  asm volatile("s_waitcnt vmcnt(6)" ::: "memory");
  __builtin_amdgcn_s_barrier();

#pragma unroll 1
  for (int i = 0; i < ITERS - 1; ++i) {
    const int t1 = 2 * i + 1, t2 = 2 * i + 2, t3 = 2 * i + 3;
    // ph1
    RDA(A0, 0); RDB(B0, 0, bf0);
    STG(pA, 1, t1, A1);
    PACE();
    PBAR(); MMQ(0, 0, bf0); __builtin_amdgcn_s_barrier();
    // ph2
    RDB(B0, 2, bf1);
    STG(pA, 0, t2, A0);
    PBAR(); MMQ(0, 2, bf1); __builtin_amdgcn_s_barrier();
    // ph3
    RDA(A0, 4);
    STG(pB, 0, t2, B0);
    PBAR(); MMQ(4, 2, bf1); __builtin_amdgcn_s_barrier();
    // ph4
    STG(pB, 1, t2, B0);
    PBAR(); MMQ(4, 0, bf0);
    asm volatile("s_waitcnt vmcnt(6)" ::: "memory");
    __builtin_amdgcn_s_barrier();
    // ph5
    RDA(A1, 0); RDB(B1, 0, bf0);
    STG(pA, 1, t2, A0);
    PACE();
    PBAR(); MMQ(0, 0, bf0); __builtin_amdgcn_s_barrier();
    // ph6
    RDB(B1, 2, bf1);
    STG(pA, 0, t3, A1);
    PBAR(); MMQ(0, 2, bf1); __builtin_amdgcn_s_barrier();
    // ph7
    RDA(A1, 4);
    STG(pB, 0, t3, B1);
    PBAR(); MMQ(4, 2, bf1); __builtin_amdgcn_s_barrier();
    // ph8
    STG(pB, 1, t3, B1);
    PBAR(); MMQ(4, 0, bf0);
    asm volatile("s_waitcnt vmcnt(6)" ::: "memory");
    __builtin_amdgcn_s_barrier();
  }

  // tail iteration (tiles 62,63): stage only ph1 (A-h1 of 63), vmcnt(0) at ph4
  RDA(A0, 0); RDB(B0, 0, bf0);
  STG(pA, 1, 63, A1);
  PACE();
  PBAR(); MMQ(0, 0, bf0); __builtin_amdgcn_s_barrier();
  RDB(B0, 2, bf1);
  PBAR(); MMQ(0, 2, bf1); __builtin_amdgcn_s_barrier();
  RDA(A0, 4);
  PBAR(); MMQ(4, 2, bf1); __builtin_amdgcn_s_barrier();
  PBAR(); MMQ(4, 0, bf0);
  asm volatile("s_waitcnt vmcnt(0)" ::: "memory");
  __builtin_amdgcn_s_barrier();
  RDA(A1, 0); RDB(B1, 0, bf0);
  PACE();
  PBAR(); MMQ(0, 0, bf0); __builtin_amdgcn_s_barrier();
  RDB(B1, 2, bf1);
  PBAR(); MMQ(0, 2, bf1); __builtin_amdgcn_s_barrier();
  RDA(A1, 4);
  PBAR(); MMQ(4, 2, bf1); __builtin_amdgcn_s_barrier();
  PBAR(); MMQ(4, 0, bf0);

  // ---------------- epilogue: LDS-shuffled coalesced fp32 stores ----------------
  // Two half-passes of 128 rows x 256 cols fp32 = 128 KB (exactly the LDS).
  // acc frag (i,j): C row = i*32 + wr*16 + (l>>4)*4 + rr, col = j*64 + wc*16 + (l&15).
  // LDS f32 addr: lr*256 + ((grp ^ (lr&7))<<2) + (c&3), grp = c>>2  (bank-spread
  // swizzle; write conflicts <=2-way = free). Read back 16B/lane, rows
  // lr = w*16 + (l>>4) + 4*jj, 256B-contiguous per 16-lane group -> nt dwordx4.
  float* ldsf = (float*)lds;
  const int r0q = (l >> 4) * 4;
  const int ccol = wc * 16 + (l & 15);
  __syncthreads();   // all waves done with K-loop LDS reads
#pragma unroll
  for (int h = 0; h < 2; ++h) {
    if (h) __syncthreads();   // previous half's readers done before overwrite
#pragma unroll
    for (int i4 = 0; i4 < 4; ++i4)
#pragma unroll
      for (int j = 0; j < 4; ++j) {
        const int lr0 = i4 * 32 + wr * 16 + r0q;
        const int c   = j * 64 + ccol;
        const int grp = c >> 2, win = c & 3;
#pragma unroll
        for (int rr = 0; rr < 4; ++rr) {
          const int lr = lr0 + rr;
          ldsf[lr * 256 + ((grp ^ (lr & 7)) << 2) + win] = acc[h * 4 + i4][j][rr];
        }
      }
    __syncthreads();
#pragma unroll
    for (int jj = 0; jj < 4; ++jj)
#pragma unroll
      for (int k = 0; k < 4; ++k) {
        const int lr = w * 16 + (l >> 4) + 4 * jj;
        const int g  = (l & 15) + 16 * k;
        f32x4 v = *(const f32x4*)&ldsf[lr * 256 + ((g ^ (lr & 7)) << 2)];
        float* cp = C + (size_t)(bm * 256 + h * 128 + lr) * Ndim + bn * 256 + 4 * g;
        __builtin_nontemporal_store(v, (f32x4*)cp);
      }
  }
}

extern "C" void kernel_launch(void* const* d_in, const int* in_sizes, int n_in,
                              void* d_out, int out_size, void* d_ws, size_t ws_size,
                              hipStream_t stream) {
  const float* x     = (const float*)d_in[0];
  const float* qw    = (const float*)d_in[1];
  const float* scale = (const float*)d_in[2];
  float* out = (float*)d_out;

  unsigned short* xb = (unsigned short*)d_ws;                 // 67.1 MB
  unsigned short* wb = xb + (size_t)Mdim * Kdim;              // +33.6 MB

  (void)hipFuncSetAttribute((const void*)gemm_kernel,
                            hipFuncAttributeMaxDynamicSharedMemorySize, 131072);

  const long nchunks = (long)Mdim * Kdim / 8 + (long)Ndim * Kdim / 8;  // 6291456
  cvt_kernel<<<(int)(nchunks / 256), 256, 0, stream>>>(x, qw, scale, xb, wb);

  gemm_kernel<<<(Mdim / 256) * (Ndim / 256), 512, 131072, stream>>>(xb, wb, out);
}